// Round 9
// baseline (59380.768 us; speedup 1.0000x reference)
//
#include <hip/hip_runtime.h>

// LayerNorm-LSTM, S=512 B=64 I=H=512 L=2, all I/O f32, all compute f32
// (recurrence is chaotic: bf16 W => absmax ~1.4 FAIL; f32 ordering noise
//  => ~0.016 PASS. So: f32 VALU only, deterministic reduction orders.)
//
// Persistent kernel: 256 WGs x 256 thr, 1 WG/CU (158.7 KB LDS).
//   wg = [layer(2)][w(128)]; WG owns rows 0..63 x hc [4w,4w+4) x 4 gates.
//   Per tick: 1024 outputs = [x_t;h](64x1024) @ Wslice(1024x16), W in LDS.
//   4 waves split K (32-chunks), thread tile 4 rows x 4 cols.
//   A staged in 8 chunks of 128 k, double-buffered LDS.
//   L1 pipelined behind L0; y0 staged via out[t] (L0 writes once at its tick
//   t; L1 reads then overwrites at its tick t, gated by L0's counter).
// Sync (round 9 change): per-layer 128-WG counter barriers instead of
// cg::grid.sync (measured ~45us/call -> 90us/tick, 93% of runtime).
// Pattern: agent-scope RMW arrival (RELEASE) + relaxed spin + ACQUIRE fence.
// L1->L0 one-way wait on L0's counter value (no cycle => deadlock-free;
// co-residency guaranteed: grid = 256 = #CUs at 1 WG/CU).

#define NTH 256

typedef float f32x4 __attribute__((ext_vector_type(4)));

__device__ __forceinline__ float sigm(float x) { return 1.f / (1.f + __expf(-x)); }
__device__ __forceinline__ float tanh_f(float x) { return 2.f / (1.f + __expf(-2.f * x)) - 1.f; }

// 128-WG barrier on one counter; target = 128 * (call number).
__device__ __forceinline__ void gbar(unsigned int* ctr, unsigned int target) {
  __threadfence();                    // order this WG's prior stores
  __syncthreads();
  if (threadIdx.x == 0) {
    __hip_atomic_fetch_add(ctr, 1u, __ATOMIC_RELEASE, __HIP_MEMORY_SCOPE_AGENT);
    long guard = 0;
    while (__hip_atomic_load(ctr, __ATOMIC_RELAXED, __HIP_MEMORY_SCOPE_AGENT) < target) {
      if (++guard > (1L << 26)) break;   // safety valve; never hit when healthy
    }
  }
  __syncthreads();
  __builtin_amdgcn_fence(__ATOMIC_ACQUIRE, "agent");  // invalidate stale cache
}

// one-way wait: block until *ctr >= target (producer's counter).
__device__ __forceinline__ void wait_ctr(const unsigned int* ctr, unsigned int target) {
  if (threadIdx.x == 0) {
    long guard = 0;
    while (__hip_atomic_load(ctr, __ATOMIC_RELAXED, __HIP_MEMORY_SCOPE_AGENT) < target) {
      if (++guard > (1L << 26)) break;
    }
  }
  __syncthreads();
  __builtin_amdgcn_fence(__ATOMIC_ACQUIRE, "agent");
}

__global__ __launch_bounds__(NTH, 1)
void lstm_pk(const float* __restrict__ inputs, const float* __restrict__ h0,
             const float* __restrict__ c0,
             const float* __restrict__ wx0, const float* __restrict__ wx1,
             const float* __restrict__ wh0, const float* __restrict__ wh1,
             const float* __restrict__ bias, const float* __restrict__ gamma_,
             const float* __restrict__ beta_,
             float* __restrict__ out,
             unsigned int* bars,                // [2] counters (padded)
             float* __restrict__ slots,         // [2][64][4][2][128] f32
             float* __restrict__ h_state)       // [2][64][512] f32
{
  extern __shared__ float lds[];
  float* W_lds = lds;                   // [1024][16]        16384 f = 64 KB
  float* A_lds = lds + 16384;           // [2][128][68]      17408 f = 68 KB
  float* part  = lds + 16384 + 17408;   // [4][64][17]        4352 f = 17 KB
  float* gates = part + 4352;           // [64][16]           1024 f =  4 KB
  float* minv  = gates + 1024;          // [64][4][2]          512 f =  2 KB
  // total 39680 floats = 158720 B

  const int tid = threadIdx.x;
  const int wg = blockIdx.x;
  const int layer = wg >> 7;
  const int w = wg & 127;            // hc slice [4w, 4w+4)
  const int wavet = tid >> 6;        // K-split group 0..3
  const int lane = tid & 63;
  const int rq = lane & 15;          // row quad -> rows 4rq..4rq+3
  const int gq = lane >> 4;          // gate (col quad)
  const int srow = tid >> 2;         // stats/cell row 0..63
  const int sg = tid & 3;            // stats gate / cell hc-within-slice
  const int hc = 4 * w + sg;         // global h column (cell phase)

  const float* Wx = layer ? wx1 : wx0;
  const float* Wh = layer ? wh1 : wh0;

  // ---- one-time: W slice -> LDS. W_lds[k][g*4+j] = W[k][g*512+4w+j]
  for (int i = 0; i < 16; ++i) {
    int e = tid + i * 256;           // [0,4096)
    int k = e >> 2, g = e & 3;
    const float* src = (k < 512) ? (Wx + (size_t)k * 2048)
                                 : (Wh + (size_t)(k - 512) * 2048);
    f32x4 v = *(const f32x4*)(src + g * 512 + 4 * w);
    *(f32x4*)&W_lds[k * 16 + g * 4] = v;
  }

  f32x4 biasr = *(const f32x4*)(bias + layer * 2048 + sg * 512 + 4 * w);
  float gam[4], bet[4];
#pragma unroll
  for (int g = 0; g < 4; ++g) {
    gam[g] = gamma_[layer * 2048 + g * 512 + hc];
    bet[g] = beta_[layer * 2048 + g * 512 + hc];
  }
  float c_st = c0[layer * 32768 + srow * 512 + hc];

  float* slotL = slots + (size_t)layer * 65536;   // [64][4][2][128]
  float* hstL = h_state + layer * 32768;
  unsigned int* myctr = bars + layer * 32;        // own layer's barrier ctr
  const unsigned int* l0ctr = bars;               // layer-0 counter (128B apart)

  const int strow = rq + 16 * wavet;              // staging row for this thread
  unsigned int calls = 0;                         // my barrier call count

  for (int tau = 0; tau <= 512; ++tau) {
    const int t = layer ? (tau - 1) : tau;
    const bool active = ((unsigned)t < 512u);

    if (active) {
      const float* xsrc = (layer ? out : inputs) + (size_t)t * 32768;
      const float* hsrc = (t == 0) ? (h0 + layer * 32768) : hstL;

      f32x4 acc[4];
#pragma unroll
      for (int r = 0; r < 4; ++r) acc[r] = (f32x4){0.f, 0.f, 0.f, 0.f};

      f32x4 st[8];
      auto LOADC = [&](int c) {            // chunk c: c>=4 -> h, else x
        const float* src = (c >= 4) ? hsrc : xsrc;
        const int koff = (c & 3) * 128;
#pragma unroll
        for (int i = 0; i < 8; ++i) {
          int kq = gq + 4 * i;             // 0..31
          st[i] = *(const f32x4*)(src + strow * 512 + koff + 4 * kq);
        }
      };
      auto WRITEC = [&](int b) {           // regs -> A_lds[b], [k][row]
        float* dst = A_lds + b * 8704;
#pragma unroll
        for (int i = 0; i < 8; ++i) {
          int kq = gq + 4 * i;
#pragma unroll
          for (int j = 0; j < 4; ++j)
            dst[(4 * kq + j) * 68 + strow] = st[i][j];
        }
      };
      auto COMPUTEC = [&](int c, int b) {
        const float* Ab = A_lds + b * 8704;
        const int kg = c * 128 + wavet * 32;
#pragma unroll 8
        for (int kk = 0; kk < 32; ++kk) {
          int k = wavet * 32 + kk;
          f32x4 av = *(const f32x4*)&Ab[k * 68 + 4 * rq];
          f32x4 wv = *(const f32x4*)&W_lds[(kg + kk) * 16 + gq * 4];
          acc[0] += av[0] * wv;
          acc[1] += av[1] * wv;
          acc[2] += av[2] * wv;
          acc[3] += av[3] * wv;
        }
      };

      LOADC(4);                            // h-half first
      WRITEC(0);
      __syncthreads();
#pragma unroll 1
      for (int co = 0; co < 8; ++co) {
        int c = (co + 4) & 7;              // 4,5,6,7,0,1,2,3
        if (co < 7) {
          if (layer == 1 && co == 3)       // about to load x chunk 0 = y0(t)
            wait_ctr(l0ctr, 128u * (2u * (unsigned)t + 2u));
          LOADC((co + 5) & 7);
        }
        COMPUTEC(c, co & 1);
        if (co < 7) WRITEC((co + 1) & 1);
        __syncthreads();
      }

      // partials -> LDS (part[m][row][g*4+c], pad 17)
#pragma unroll
      for (int r = 0; r < 4; ++r)
#pragma unroll
        for (int cc = 0; cc < 4; ++cc)
          part[(wavet * 64 + 4 * rq + r) * 17 + gq * 4 + cc] = acc[r][cc];
      __syncthreads();

      // sum 4 K-groups + bias -> gates LDS + stats partial -> own slot
      {
        f32x4 pre;
#pragma unroll
        for (int cc = 0; cc < 4; ++cc) {
          float v = biasr[cc];
          v += part[(0 * 64 + srow) * 17 + sg * 4 + cc];
          v += part[(1 * 64 + srow) * 17 + sg * 4 + cc];
          v += part[(2 * 64 + srow) * 17 + sg * 4 + cc];
          v += part[(3 * 64 + srow) * 17 + sg * 4 + cc];
          pre[cc] = v;
        }
        *(f32x4*)&gates[srow * 16 + sg * 4] = pre;
        float s = ((pre[0] + pre[1]) + pre[2]) + pre[3];
        float ss = ((pre[0] * pre[0] + pre[1] * pre[1]) + pre[2] * pre[2]) + pre[3] * pre[3];
        slotL[((srow * 4 + sg) * 2 + 0) * 128 + w] = s;
        slotL[((srow * 4 + sg) * 2 + 1) * 128 + w] = ss;
      }
    }

    ++calls; gbar(myctr, 128u * calls);    // barrier A: stats slots complete

    if (active) {
      // deterministic reduce of 128 slices (redundant in every WG, same order)
      {
        const float* sp = slotL + (size_t)(srow * 4 + sg) * 256;
        float S = 0.f, SS = 0.f;
        for (int q = 0; q < 128; q += 4) {
          f32x4 v = *(const f32x4*)&sp[q];
          S = (((S + v[0]) + v[1]) + v[2]) + v[3];
        }
        for (int q = 0; q < 128; q += 4) {
          f32x4 v = *(const f32x4*)&sp[128 + q];
          SS = (((SS + v[0]) + v[1]) + v[2]) + v[3];
        }
        float mu = S * (1.f / 512.f);
        float var = SS * (1.f / 512.f) - mu * mu;
        minv[(srow * 4 + sg) * 2 + 0] = mu;
        minv[(srow * 4 + sg) * 2 + 1] = rsqrtf(fmaxf(var, 0.f) + 1e-5f);
      }
      __syncthreads();

      // normalize + cell (thread owns (srow, hc))
      {
        float gv[4];
#pragma unroll
        for (int g = 0; g < 4; ++g) {
          float pre = gates[srow * 16 + g * 4 + sg];
          gv[g] = (pre - minv[(srow * 4 + g) * 2]) * minv[(srow * 4 + g) * 2 + 1] * gam[g] + bet[g];
        }
        float ig = sigm(gv[0]);
        float fg = sigm(gv[1]);
        float og = sigm(gv[2]);
        float ug = tanh_f(gv[3]);
        c_st = fg * c_st + ig * ug;
        float hv = og * tanh_f(c_st);
        hstL[srow * 512 + hc] = hv;
        out[(size_t)t * 32768 + srow * 512 + hc] = hv;  // L0: y0 stage; L1: final
        if (t == 511) {
          out[16777216 + layer * 32768 + srow * 512 + hc] = hv;    // h_n
          out[16842752 + layer * 32768 + srow * 512 + hc] = c_st;  // c_n
        }
      }
    }

    ++calls; gbar(myctr, 128u * calls);    // barrier B: h / y0 published
  }
}

extern "C" void kernel_launch(void* const* d_in, const int* in_sizes, int n_in,
                              void* d_out, int out_size, void* d_ws, size_t ws_size,
                              hipStream_t stream) {
  const float* inputs = (const float*)d_in[0];
  const float* h0 = (const float*)d_in[1];
  const float* c0 = (const float*)d_in[2];
  const float* wx0 = (const float*)d_in[3];
  const float* wx1 = (const float*)d_in[4];
  const float* wh0 = (const float*)d_in[5];
  const float* wh1 = (const float*)d_in[6];
  const float* bias = (const float*)d_in[7];
  const float* gamma_ = (const float*)d_in[8];
  const float* beta_ = (const float*)d_in[9];
  float* out = (float*)d_out;

  char* ws = (char*)d_ws;
  unsigned int* bars = (unsigned int*)ws;         // 2 counters, 128 B apart
  float* slots = (float*)(ws + 4096);             // 524288 B
  float* h_state = (float*)(ws + 4096 + 524288);  // 262144 B

  const int smem_bytes = 158720;
  hipFuncSetAttribute((const void*)lstm_pk,
                      hipFuncAttributeMaxDynamicSharedMemorySize, smem_bytes);
  hipMemsetAsync(ws, 0, 4096, stream);            // zero barrier counters

  hipLaunchKernelGGL(lstm_pk, dim3(256), dim3(NTH), smem_bytes, stream,
                     inputs, h0, c0, wx0, wx1, wh0, wh1, bias, gamma_, beta_,
                     out, bars, slots, h_state);
}

// Round 10
// 34630.206 us; speedup vs baseline: 1.7147x; 1.7147x over previous
//
#include <hip/hip_runtime.h>

// LayerNorm-LSTM, S=512 B=64 I=H=512 L=2, all I/O f32, all compute f32
// (recurrence is chaotic: bf16 anywhere in the loop => absmax ~1.4 FAIL;
//  f32 ordering noise => ~0.016 PASS. f32 VALU only, deterministic orders.)
//
// Persistent kernel: 256 WGs x 256 thr, 1 WG/CU (158.7 KB LDS).
//   wg = [layer(2)][w(128)]; WG owns rows 0..63 x hc [4w,4w+4) x 4 gates.
//   Per tick: 1024 outputs = [x_t;h](64x1024) @ Wslice(1024x16), W in LDS.
//   4 waves split K, thread tile 4 rows x 4 cols; A double-buffered in LDS.
//
// Sync evolution: grid.sync ~45us/call (R8, 49ms); single-counter barrier
// ~55us/call -- 128 serialized RMWs on one line (R9, 58ms). R10: flag-array
// barrier: each WG RELEASE-RMWs its OWN 128B-padded flag (parallel,
// uncontended), waiters poll 128 flags (1 lane each) + __syncthreads_and +
// ACQUIRE agent fence (exact R9-proven fence recipe, contention removed).
// Split arrive/wait: L0 computes x-half before waiting on h(t-1); L1
// computes h-half before waiting on y0(t) (one-way L1->L0, no cycle).

#define NTH 256

typedef float f32x4 __attribute__((ext_vector_type(4)));

__device__ __forceinline__ float sigm(float x) { return 1.f / (1.f + __expf(-x)); }
__device__ __forceinline__ float tanh_f(float x) { return 2.f / (1.f + __expf(-2.f * x)) - 1.f; }

// arrive: bump my own padded flag (uncontended RELEASE RMW, R9-proven op)
__device__ __forceinline__ void arrive(unsigned int* flag) {
  __syncthreads();                 // WG's prior LDS/global work done
  if (threadIdx.x == 0) {
    __threadfence();
    __hip_atomic_fetch_add(flag, 1u, __ATOMIC_RELEASE, __HIP_MEMORY_SCOPE_AGENT);
  }
}

// waitall: block until flags[i*32] >= target for all i<128, then acquire.
__device__ __forceinline__ void waitall(const unsigned int* flags, unsigned int target) {
  long guard = 0;
  for (;;) {
    int ok = 1;
    if (threadIdx.x < 128) {
      unsigned int v = __hip_atomic_load(&flags[threadIdx.x * 32],
                                         __ATOMIC_RELAXED, __HIP_MEMORY_SCOPE_AGENT);
      ok = (v >= target);
    }
    if (__syncthreads_and(ok)) break;
    if (++guard > (1L << 22)) break;   // safety valve; never hit when healthy
  }
  __builtin_amdgcn_fence(__ATOMIC_ACQUIRE, "agent");  // invalidate stale cache
}

__global__ __launch_bounds__(NTH, 1)
void lstm_pk(const float* __restrict__ inputs, const float* __restrict__ h0,
             const float* __restrict__ c0,
             const float* __restrict__ wx0, const float* __restrict__ wx1,
             const float* __restrict__ wh0, const float* __restrict__ wh1,
             const float* __restrict__ bias, const float* __restrict__ gamma_,
             const float* __restrict__ beta_,
             float* __restrict__ out,
             unsigned int* flags,               // [4][128][32] u32 (fA0,fA1,fB0,fB1)
             float* __restrict__ slots,         // [2][64][4][2][128] f32
             float* __restrict__ h_state)       // [2][64][512] f32
{
  extern __shared__ float lds[];
  float* W_lds = lds;                   // [1024][16]        16384 f = 64 KB
  float* A_lds = lds + 16384;           // [2][128][68]      17408 f = 68 KB
  float* part  = lds + 16384 + 17408;   // [4][64][17]        4352 f = 17 KB
  float* gates = part + 4352;           // [64][16]           1024 f =  4 KB
  float* minv  = gates + 1024;          // [64][4][2]          512 f =  2 KB
  // total 39680 floats = 158720 B

  const int tid = threadIdx.x;
  const int wg = blockIdx.x;
  const int layer = wg >> 7;
  const int w = wg & 127;            // hc slice [4w, 4w+4)
  const int wavet = tid >> 6;        // K-split group 0..3
  const int lane = tid & 63;
  const int rq = lane & 15;          // row quad -> rows 4rq..4rq+3
  const int gq = lane >> 4;          // gate (col quad)
  const int srow = tid >> 2;         // stats/cell row 0..63
  const int sg = tid & 3;            // stats gate / cell hc-within-slice
  const int hc = 4 * w + sg;         // global h column (cell phase)

  const float* Wx = layer ? wx1 : wx0;
  const float* Wh = layer ? wh1 : wh0;

  // ---- one-time: W slice -> LDS. W_lds[k][g*4+j] = W[k][g*512+4w+j]
  for (int i = 0; i < 16; ++i) {
    int e = tid + i * 256;           // [0,4096)
    int k = e >> 2, g = e & 3;
    const float* src = (k < 512) ? (Wx + (size_t)k * 2048)
                                 : (Wh + (size_t)(k - 512) * 2048);
    f32x4 v = *(const f32x4*)(src + g * 512 + 4 * w);
    *(f32x4*)&W_lds[k * 16 + g * 4] = v;
  }

  f32x4 biasr = *(const f32x4*)(bias + layer * 2048 + sg * 512 + 4 * w);
  float gam[4], bet[4];
#pragma unroll
  for (int g = 0; g < 4; ++g) {
    gam[g] = gamma_[layer * 2048 + g * 512 + hc];
    bet[g] = beta_[layer * 2048 + g * 512 + hc];
  }
  float c_st = c0[layer * 32768 + srow * 512 + hc];

  float* slotL = slots + (size_t)layer * 65536;   // [64][4][2][128]
  float* hstL = h_state + layer * 32768;
  unsigned int* fAmy = flags + layer * 4096;       // my layer's A flags
  unsigned int* fBmy = flags + 8192 + layer * 4096;
  const unsigned int* fB0 = flags + 8192;          // layer-0 B flags

  const int strow = rq + 16 * wavet;              // staging row for this thread
  const int first = layer ? 4 : 0;                // L0: x-half first; L1: h-half

  for (int t = 0; t < 512; ++t) {
    const float* xsrc = (layer ? out : inputs) + (size_t)t * 32768;
    const float* hsrc = (t == 0) ? (h0 + layer * 32768) : hstL;

    f32x4 acc[4];
#pragma unroll
    for (int r = 0; r < 4; ++r) acc[r] = (f32x4){0.f, 0.f, 0.f, 0.f};

    f32x4 st[8];
    auto LOADC = [&](int c) {            // chunk c: c>=4 -> h, else x
      const float* src = (c >= 4) ? hsrc : xsrc;
      const int koff = (c & 3) * 128;
#pragma unroll
      for (int i = 0; i < 8; ++i) {
        int kq = gq + 4 * i;             // 0..31
        st[i] = *(const f32x4*)(src + strow * 512 + koff + 4 * kq);
      }
    };
    auto WRITEC = [&](int b) {           // regs -> A_lds[b], [k][row]
      float* dst = A_lds + b * 8704;
#pragma unroll
      for (int i = 0; i < 8; ++i) {
        int kq = gq + 4 * i;
#pragma unroll
        for (int j = 0; j < 4; ++j)
          dst[(4 * kq + j) * 68 + strow] = st[i][j];
      }
    };
    auto COMPUTEC = [&](int c, int b) {
      const float* Ab = A_lds + b * 8704;
      const int kg = c * 128 + wavet * 32;
#pragma unroll 8
      for (int kk = 0; kk < 32; ++kk) {
        int k = wavet * 32 + kk;
        f32x4 av = *(const f32x4*)&Ab[k * 68 + 4 * rq];
        f32x4 wv = *(const f32x4*)&W_lds[(kg + kk) * 16 + gq * 4];
        acc[0] += av[0] * wv;
        acc[1] += av[1] * wv;
        acc[2] += av[2] * wv;
        acc[3] += av[3] * wv;
      }
    };

    // L1's first load is the h-half: own h(t-1) must be published.
    if (layer == 1) waitall(fBmy, (unsigned)t);
    LOADC(first);
    WRITEC(0);
    __syncthreads();
#pragma unroll 1
    for (int co = 0; co < 8; ++co) {
      int c = (co + first) & 7;
      if (co < 7) {
        if (co == 3) {
          // about to prefetch the other half's first chunk
          if (layer == 1) waitall(fB0, (unsigned)t + 1u);  // y0(t) published
          else           waitall(fBmy, (unsigned)t);        // h(t-1) published
        }
        LOADC((c + 1) & 7);
      }
      COMPUTEC(c, co & 1);
      if (co < 7) WRITEC((co + 1) & 1);
      __syncthreads();
    }

    // partials -> LDS (part[m][row][g*4+c], pad 17)
#pragma unroll
    for (int r = 0; r < 4; ++r)
#pragma unroll
      for (int cc = 0; cc < 4; ++cc)
        part[(wavet * 64 + 4 * rq + r) * 17 + gq * 4 + cc] = acc[r][cc];
    __syncthreads();

    // sum 4 K-groups + bias -> gates LDS + stats partial -> own slot
    {
      f32x4 pre;
#pragma unroll
      for (int cc = 0; cc < 4; ++cc) {
        float v = biasr[cc];
        v += part[(0 * 64 + srow) * 17 + sg * 4 + cc];
        v += part[(1 * 64 + srow) * 17 + sg * 4 + cc];
        v += part[(2 * 64 + srow) * 17 + sg * 4 + cc];
        v += part[(3 * 64 + srow) * 17 + sg * 4 + cc];
        pre[cc] = v;
      }
      *(f32x4*)&gates[srow * 16 + sg * 4] = pre;
      float s = ((pre[0] + pre[1]) + pre[2]) + pre[3];
      float ss = ((pre[0] * pre[0] + pre[1] * pre[1]) + pre[2] * pre[2]) + pre[3] * pre[3];
      slotL[((srow * 4 + sg) * 2 + 0) * 128 + w] = s;
      slotL[((srow * 4 + sg) * 2 + 1) * 128 + w] = ss;
    }

    arrive(&fAmy[w * 32]);               // stats slots complete
    waitall(fAmy, (unsigned)t + 1u);

    // deterministic reduce of 128 slices (redundant in every WG, same order)
    {
      const float* sp = slotL + (size_t)(srow * 4 + sg) * 256;
      float S = 0.f, SS = 0.f;
      for (int q = 0; q < 128; q += 4) {
        f32x4 v = *(const f32x4*)&sp[q];
        S = (((S + v[0]) + v[1]) + v[2]) + v[3];
      }
      for (int q = 0; q < 128; q += 4) {
        f32x4 v = *(const f32x4*)&sp[128 + q];
        SS = (((SS + v[0]) + v[1]) + v[2]) + v[3];
      }
      float mu = S * (1.f / 512.f);
      float var = SS * (1.f / 512.f) - mu * mu;
      minv[(srow * 4 + sg) * 2 + 0] = mu;
      minv[(srow * 4 + sg) * 2 + 1] = rsqrtf(fmaxf(var, 0.f) + 1e-5f);
    }
    __syncthreads();

    // normalize + cell (thread owns (srow, hc))
    {
      float gv[4];
#pragma unroll
      for (int g = 0; g < 4; ++g) {
        float pre = gates[srow * 16 + g * 4 + sg];
        gv[g] = (pre - minv[(srow * 4 + g) * 2]) * minv[(srow * 4 + g) * 2 + 1] * gam[g] + bet[g];
      }
      float ig = sigm(gv[0]);
      float fg = sigm(gv[1]);
      float og = sigm(gv[2]);
      float ug = tanh_f(gv[3]);
      c_st = fg * c_st + ig * ug;
      float hv = og * tanh_f(c_st);
      hstL[srow * 512 + hc] = hv;
      out[(size_t)t * 32768 + srow * 512 + hc] = hv;  // L0: y0 stage; L1: final
      if (t == 511) {
        out[16777216 + layer * 32768 + srow * 512 + hc] = hv;    // h_n
        out[16842752 + layer * 32768 + srow * 512 + hc] = c_st;  // c_n
      }
    }

    arrive(&fBmy[w * 32]);               // h / y0 published
  }
}

extern "C" void kernel_launch(void* const* d_in, const int* in_sizes, int n_in,
                              void* d_out, int out_size, void* d_ws, size_t ws_size,
                              hipStream_t stream) {
  const float* inputs = (const float*)d_in[0];
  const float* h0 = (const float*)d_in[1];
  const float* c0 = (const float*)d_in[2];
  const float* wx0 = (const float*)d_in[3];
  const float* wx1 = (const float*)d_in[4];
  const float* wh0 = (const float*)d_in[5];
  const float* wh1 = (const float*)d_in[6];
  const float* bias = (const float*)d_in[7];
  const float* gamma_ = (const float*)d_in[8];
  const float* beta_ = (const float*)d_in[9];
  float* out = (float*)d_out;

  char* ws = (char*)d_ws;
  unsigned int* flags = (unsigned int*)ws;        // 65536 B (4x128x32 u32)
  float* slots = (float*)(ws + 65536);            // 524288 B
  float* h_state = (float*)(ws + 65536 + 524288); // 262144 B

  const int smem_bytes = 158720;
  hipFuncSetAttribute((const void*)lstm_pk,
                      hipFuncAttributeMaxDynamicSharedMemorySize, smem_bytes);
  hipMemsetAsync(ws, 0, 65536, stream);           // zero all flags

  hipLaunchKernelGGL(lstm_pk, dim3(256), dim3(NTH), smem_bytes, stream,
                     inputs, h0, c0, wx0, wx1, wh0, wh1, bias, gamma_, beta_,
                     out, flags, slots, h_state);
}

// Round 11
// 20273.924 us; speedup vs baseline: 2.9289x; 1.7081x over previous
//
#include <hip/hip_runtime.h>

// LayerNorm-LSTM, S=512 B=64 I=H=512 L=2, all I/O f32, all compute f32
// (recurrence is chaotic: bf16 anywhere => absmax ~1.4 FAIL; f32 ordering
//  noise => ~0.016 PASS. f32 VALU only, deterministic reduction orders.)
//
// Persistent kernel: 256 WGs x 256 thr, 1 WG/CU. W slice (64 KB) in LDS.
//   wg = [layer(2)][w(128)]; WG owns rows 0..63 x hc [4w,4w+4) x 4 gates.
//   Per tick: 1024 outputs = [x_t;h](64x1024) @ Wslice(1024x16).
//
// Sync evolution: grid.sync 45us/call (R8, 49ms); contended counter 55us
// (R9, 58ms); flag-array + agent fences ~23us (R10, 34.6ms). R11: remove
// fences from the hot path:
//  - ALL cross-WG-visible stores are SYSTEM-scope atomic u64 (write-through
//    to IF$; L2 stays clean) -> release flag-stores are cheap.
//  - LN stats: slot partials (SYSTEM u64) -> partitioned reduce (WG w does
//    2 (row,gate) pairs, shfl-xor tree) -> minv broadcast (SYSTEM u64).
//    No cache fences on this path (signal_fence + syncthreads vmcnt drain).
//  - h / y0: SYSTEM u64 stores by producer (1 KB/WG); consumers use cached
//    f32x4 loads gated by ONE acquire-agent fence per tick (2 for L1) --
//    the R10-proven fence recipe, count reduced ~4.5 -> 1-2.
//  - Flags: phase values 3t+1 (slots), 3t+2 (minv), 3t+3 (h/y0 posted);
//    single-writer RELEASE SYSTEM stores; waitall = 128 parallel polls.

#define NTH 256

typedef float f32x4 __attribute__((ext_vector_type(4)));

__device__ __forceinline__ float sigm(float x) { return 1.f / (1.f + __expf(-x)); }
__device__ __forceinline__ float tanh_f(float x) { return 2.f / (1.f + __expf(-2.f * x)) - 1.f; }

__device__ __forceinline__ unsigned long long pack2(float a, float b) {
  union { float f[2]; unsigned long long u; } x; x.f[0] = a; x.f[1] = b; return x.u;
}
__device__ __forceinline__ float lo2(unsigned long long u) {
  union { unsigned long long u; float f[2]; } x; x.u = u; return x.f[0];
}
__device__ __forceinline__ float hi2(unsigned long long u) {
  union { unsigned long long u; float f[2]; } x; x.u = u; return x.f[1];
}

__device__ __forceinline__ void sys_store64(unsigned long long* p, unsigned long long v) {
  __hip_atomic_store(p, v, __ATOMIC_RELAXED, __HIP_MEMORY_SCOPE_SYSTEM);
}
__device__ __forceinline__ unsigned long long sys_load64(const unsigned long long* p) {
  return __hip_atomic_load(p, __ATOMIC_RELAXED, __HIP_MEMORY_SCOPE_SYSTEM);
}

// post: all threads' prior stores drained by __syncthreads (vmcnt0+barrier),
// then single-writer RELEASE store of the phase value.
__device__ __forceinline__ void post(unsigned int* flag, unsigned int val) {
  __syncthreads();
  if (threadIdx.x == 0)
    __hip_atomic_store(flag, val, __ATOMIC_RELEASE, __HIP_MEMORY_SCOPE_SYSTEM);
}

// waitall: block until flags[i*32] >= target for all i<128 (compiler-only
// acquire; pair with an explicit agent acquire fence before CACHED reads).
__device__ __forceinline__ void waitall(const unsigned int* flags, unsigned int target) {
  long guard = 0;
  for (;;) {
    int ok = 1;
    if (threadIdx.x < 128) {
      unsigned int v = __hip_atomic_load(&flags[threadIdx.x * 32],
                                         __ATOMIC_RELAXED, __HIP_MEMORY_SCOPE_SYSTEM);
      ok = (v >= target);
    }
    if (__syncthreads_and(ok)) break;
    if (++guard > (1L << 22)) break;   // safety valve; never hit when healthy
  }
  __atomic_signal_fence(__ATOMIC_ACQUIRE);
}

__global__ __launch_bounds__(NTH, 1)
void lstm_pk(const float* __restrict__ inputs, const float* __restrict__ h0,
             const float* __restrict__ c0,
             const float* __restrict__ wx0, const float* __restrict__ wx1,
             const float* __restrict__ wh0, const float* __restrict__ wh1,
             const float* __restrict__ bias, const float* __restrict__ gamma_,
             const float* __restrict__ beta_,
             float* __restrict__ out,
             unsigned int* flags,               // [2][128][32] u32
             unsigned long long* slots,         // [2][256 pair][128 slice] u64
             unsigned long long* minv_g,        // [2][256 pair] u64
             float* __restrict__ h_state)       // [2][64][512] f32
{
  extern __shared__ float lds[];
  float* W_lds = lds;                   // [1024][16]        16384 f = 64 KB
  float* A_lds = lds + 16384;           // [2][128][68]      17408 f = 68 KB
  float* part  = lds + 16384 + 17408;   // [4][64][17]        4352 f = 17 KB
  float* gates = part + 4352;           // [64][16]           1024 f =  4 KB
  float* minv  = gates + 1024;          // [256 pair][2]       512 f =  2 KB
  // total 39680 floats = 158720 B

  const int tid = threadIdx.x;
  const int wg = blockIdx.x;
  const int layer = wg >> 7;
  const int w = wg & 127;            // hc slice [4w, 4w+4)
  const int wavet = tid >> 6;        // K-split group 0..3
  const int lane = tid & 63;
  const int rq = lane & 15;          // row quad -> rows 4rq..4rq+3
  const int gq = lane >> 4;          // gate (col quad)
  const int srow = tid >> 2;         // stats/cell row 0..63
  const int sg = tid & 3;            // stats gate / cell hc-within-slice
  const int hc = 4 * w + sg;         // global h column (cell phase)

  const float* Wx = layer ? wx1 : wx0;
  const float* Wh = layer ? wh1 : wh0;

  // ---- one-time: W slice -> LDS. W_lds[k][g*4+j] = W[k][g*512+4w+j]
  for (int i = 0; i < 16; ++i) {
    int e = tid + i * 256;           // [0,4096)
    int k = e >> 2, g = e & 3;
    const float* src = (k < 512) ? (Wx + (size_t)k * 2048)
                                 : (Wh + (size_t)(k - 512) * 2048);
    f32x4 v = *(const f32x4*)(src + g * 512 + 4 * w);
    *(f32x4*)&W_lds[k * 16 + g * 4] = v;
  }

  f32x4 biasr = *(const f32x4*)(bias + layer * 2048 + sg * 512 + 4 * w);
  float gam[4], bet[4];
#pragma unroll
  for (int g = 0; g < 4; ++g) {
    gam[g] = gamma_[layer * 2048 + g * 512 + hc];
    bet[g] = beta_[layer * 2048 + g * 512 + hc];
  }
  float c_st = c0[layer * 32768 + srow * 512 + hc];

  unsigned long long* slotL = slots + (size_t)layer * 32768;  // [256][128]
  unsigned long long* minvL = minv_g + layer * 256;
  float* hstL = h_state + layer * 32768;
  unsigned int* fmyL = flags + layer * 4096;     // my layer's 128 flags
  unsigned int* myflag = fmyL + w * 32;
  const unsigned int* fL0 = flags;               // layer-0 flags

  const int strow = rq + 16 * wavet;             // staging row for this thread
  const int first = layer ? 4 : 0;               // L1: h-half first

  for (int t = 0; t < 512; ++t) {
    const unsigned int t3 = 3u * (unsigned)t;
    const float* xsrc = (layer ? out : inputs) + (size_t)t * 32768;
    const float* hsrc = (t == 0) ? (h0 + layer * 32768) : hstL;

    // L1 starts with the h-half: own-layer h(t-1) must be posted & visible.
    if (layer == 1 && t > 0) {
      waitall(fmyL, t3);
      __builtin_amdgcn_fence(__ATOMIC_ACQUIRE, "agent");
    }

    f32x4 acc[4];
#pragma unroll
    for (int r = 0; r < 4; ++r) acc[r] = (f32x4){0.f, 0.f, 0.f, 0.f};

    f32x4 st[8];
    auto LOADC = [&](int c) {            // chunk c: c>=4 -> h, else x
      const float* src = (c >= 4) ? hsrc : xsrc;
      const int koff = (c & 3) * 128;
#pragma unroll
      for (int i = 0; i < 8; ++i) {
        int kq = gq + 4 * i;             // 0..31
        st[i] = *(const f32x4*)(src + strow * 512 + koff + 4 * kq);
      }
    };
    auto WRITEC = [&](int b) {           // regs -> A_lds[b], [k][row]
      float* dst = A_lds + b * 8704;
#pragma unroll
      for (int i = 0; i < 8; ++i) {
        int kq = gq + 4 * i;
#pragma unroll
        for (int j = 0; j < 4; ++j)
          dst[(4 * kq + j) * 68 + strow] = st[i][j];
      }
    };
    auto COMPUTEC = [&](int c, int b) {
      const float* Ab = A_lds + b * 8704;
      const int kg = c * 128 + wavet * 32;
#pragma unroll 8
      for (int kk = 0; kk < 32; ++kk) {
        int k = wavet * 32 + kk;
        f32x4 av = *(const f32x4*)&Ab[k * 68 + 4 * rq];
        f32x4 wv = *(const f32x4*)&W_lds[(kg + kk) * 16 + gq * 4];
        acc[0] += av[0] * wv;
        acc[1] += av[1] * wv;
        acc[2] += av[2] * wv;
        acc[3] += av[3] * wv;
      }
    };

    LOADC(first);
    WRITEC(0);
    __syncthreads();
#pragma unroll 1
    for (int co = 0; co < 8; ++co) {
      int c = (co + first) & 7;
      if (co < 7) {
        if (co == 3) {
          // about to prefetch the other half's first chunk
          if (layer == 1) {              // x-half = y0(t): L0 posted 3t+3
            waitall(fL0, t3 + 3u);
            __builtin_amdgcn_fence(__ATOMIC_ACQUIRE, "agent");
          } else if (t > 0) {            // h-half: own h(t-1) posted
            waitall(fmyL, t3);
            __builtin_amdgcn_fence(__ATOMIC_ACQUIRE, "agent");
          }
        }
        LOADC((c + 1) & 7);
      }
      COMPUTEC(c, co & 1);
      if (co < 7) WRITEC((co + 1) & 1);
      __syncthreads();
    }

    // partials -> LDS (part[m][row][g*4+c], pad 17)
#pragma unroll
    for (int r = 0; r < 4; ++r)
#pragma unroll
      for (int cc = 0; cc < 4; ++cc)
        part[(wavet * 64 + 4 * rq + r) * 17 + gq * 4 + cc] = acc[r][cc];
    __syncthreads();

    // sum 4 K-groups + bias -> gates LDS; stats partial -> own slot (SYSTEM)
    {
      f32x4 pre;
#pragma unroll
      for (int cc = 0; cc < 4; ++cc) {
        float v = biasr[cc];
        v += part[(0 * 64 + srow) * 17 + sg * 4 + cc];
        v += part[(1 * 64 + srow) * 17 + sg * 4 + cc];
        v += part[(2 * 64 + srow) * 17 + sg * 4 + cc];
        v += part[(3 * 64 + srow) * 17 + sg * 4 + cc];
        pre[cc] = v;
      }
      *(f32x4*)&gates[srow * 16 + sg * 4] = pre;
      float s = ((pre[0] + pre[1]) + pre[2]) + pre[3];
      float ss = ((pre[0] * pre[0] + pre[1] * pre[1]) + pre[2] * pre[2]) + pre[3] * pre[3];
      sys_store64(&slotL[(size_t)tid * 128 + w], pack2(s, ss));  // pair = tid
    }
    post(myflag, t3 + 1u);               // slots posted
    waitall(fmyL, t3 + 1u);

    // partitioned reduce: WG w reduces pairs {2w, 2w+1} (waves 0 and 1)
    if (tid < 128) {
      const int pr = 2 * w + (tid >> 6);
      unsigned long long a = sys_load64(&slotL[(size_t)pr * 128 + lane]);
      unsigned long long b = sys_load64(&slotL[(size_t)pr * 128 + lane + 64]);
      float s = lo2(a) + lo2(b);
      float ss = hi2(a) + hi2(b);
#pragma unroll
      for (int k2 = 0; k2 < 6; ++k2) {   // deterministic butterfly over 64 lanes
        s += __shfl_xor(s, 1 << k2);
        ss += __shfl_xor(ss, 1 << k2);
      }
      if (lane == 0) {
        float mu = s * (1.f / 512.f);
        float var = ss * (1.f / 512.f) - mu * mu;
        float inv = rsqrtf(fmaxf(var, 0.f) + 1e-5f);
        sys_store64(&minvL[pr], pack2(mu, inv));
      }
    }
    post(myflag, t3 + 2u);               // minv posted
    waitall(fmyL, t3 + 2u);

    // gather minv (SYSTEM) -> LDS
    if (tid < 128) {
#pragma unroll
      for (int j = 0; j < 2; ++j) {
        int pr = tid + 128 * j;
        unsigned long long u = sys_load64(&minvL[pr]);
        minv[pr * 2 + 0] = lo2(u);
        minv[pr * 2 + 1] = hi2(u);
      }
    }
    __syncthreads();

    // normalize + cell (thread owns (srow, hc))
    {
      float gv[4];
#pragma unroll
      for (int g = 0; g < 4; ++g) {
        float pre = gates[srow * 16 + g * 4 + sg];
        gv[g] = (pre - minv[(srow * 4 + g) * 2]) * minv[(srow * 4 + g) * 2 + 1] * gam[g] + bet[g];
      }
      float ig = sigm(gv[0]);
      float fg = sigm(gv[1]);
      float og = sigm(gv[2]);
      float ug = tanh_f(gv[3]);
      c_st = fg * c_st + ig * ug;
      float hv = og * tanh_f(c_st);

      // pair-pack (sg even stores {sg, sg+1}) and SYSTEM-store h and y
      float hv2 = __shfl_down(hv, 1);
      float cv2 = __shfl_down(c_st, 1);
      if ((sg & 1) == 0) {
        unsigned long long hp = pack2(hv, hv2);
        sys_store64((unsigned long long*)&hstL[srow * 512 + hc], hp);
        sys_store64((unsigned long long*)&out[(size_t)t * 32768 + srow * 512 + hc], hp);
        if (t == 511) {
          sys_store64((unsigned long long*)&out[16777216 + layer * 32768 + srow * 512 + hc], hp);
          sys_store64((unsigned long long*)&out[16842752 + layer * 32768 + srow * 512 + hc],
                      pack2(c_st, cv2));
        }
      }
    }
    post(myflag, t3 + 3u);               // h / y0 posted
  }
}

extern "C" void kernel_launch(void* const* d_in, const int* in_sizes, int n_in,
                              void* d_out, int out_size, void* d_ws, size_t ws_size,
                              hipStream_t stream) {
  const float* inputs = (const float*)d_in[0];
  const float* h0 = (const float*)d_in[1];
  const float* c0 = (const float*)d_in[2];
  const float* wx0 = (const float*)d_in[3];
  const float* wx1 = (const float*)d_in[4];
  const float* wh0 = (const float*)d_in[5];
  const float* wh1 = (const float*)d_in[6];
  const float* bias = (const float*)d_in[7];
  const float* gamma_ = (const float*)d_in[8];
  const float* beta_ = (const float*)d_in[9];
  float* out = (float*)d_out;

  char* ws = (char*)d_ws;
  unsigned int* flags = (unsigned int*)ws;                       // 32 KB (pad 64K)
  unsigned long long* slots = (unsigned long long*)(ws + 65536); // 512 KB
  unsigned long long* minv_g = (unsigned long long*)(ws + 65536 + 524288); // 4 KB
  float* h_state = (float*)(ws + 65536 + 524288 + 4096);         // 256 KB

  const int smem_bytes = 158720;
  hipFuncSetAttribute((const void*)lstm_pk,
                      hipFuncAttributeMaxDynamicSharedMemorySize, smem_bytes);
  hipMemsetAsync(ws, 0, 65536, stream);           // zero flags

  hipLaunchKernelGGL(lstm_pk, dim3(256), dim3(NTH), smem_bytes, stream,
                     inputs, h0, c0, wx0, wx1, wh0, wh1, bias, gamma_, beta_,
                     out, flags, slots, minv_g, h_state);
}